// Round 1
// baseline (93.047 us; speedup 1.0000x reference)
//
#include <hip/hip_runtime.h>
#include <hip/hip_bf16.h>

// Disable FMA contraction globally: the coordinate transform
// (p+1)*scale-0.5 must round exactly like numpy float32, or floor()
// can flip a cell index and change which octree keys we look up.
#pragma clang fp contract(off)

#define K_BITS 18  // bucket table: 2^18 buckets over the 2^26 keyspace

// ---------------------------------------------------------------------------
// Kernel A: bucket table build.  tab[j] = lower_bound(keys, j << S), j in [0,NB]
// ---------------------------------------------------------------------------
__global__ __launch_bounds__(256) void octi_build_tab(
    const int* __restrict__ keys, int H, const int* __restrict__ depth_ptr,
    int* __restrict__ tab) {
  const int NB = 1 << K_BITS;
  int j = blockIdx.x * 256 + threadIdx.x;
  if (j > NB) return;
  int depth = *depth_ptr;
  int kb = 3 * depth + 2;                 // total key bits (batch < 4)
  int S = kb > K_BITS ? kb - K_BITS : 0;  // shift: bucket = key >> S
  long long target = (long long)j << S;   // j == NB gives key past end -> H
  int lo = 0, hi = H;
  while (lo < hi) {
    int mid = (lo + hi) >> 1;
    if ((long long)keys[mid] < target) lo = mid + 1; else hi = mid;
  }
  tab[j] = lo;
}

// ---------------------------------------------------------------------------
// Kernel B: main interpolation, C == 32 fast path.
// 8 lanes per point: lane = corner index (search phase) and
// channel-quad index (gather/write phase, float4 each).
// ---------------------------------------------------------------------------
__global__ __launch_bounds__(256) void octi_interp32(
    const float* __restrict__ data, const float* __restrict__ pts,
    const int* __restrict__ keys, const int* __restrict__ depth_ptr,
    const int* __restrict__ tab, float* __restrict__ out,
    int N, int H) {
  int t = blockIdx.x * 256 + threadIdx.x;
  int i = t >> 3;   // point index
  if (i >= N) return;
  int l = t & 7;    // corner / channel-quad index

  int depth = *depth_ptr;
  int kb = 3 * depth + 2;
  int S = kb > K_BITS ? kb - K_BITS : 0;
  float scale = (float)(1 << (depth - 1));

  float4 p = reinterpret_cast<const float4*>(pts)[i];

  // exact numpy-f32 sequence: (p + 1.0f) * scale - 0.5f  (no contraction)
  float xf = (p.x + 1.0f) * scale - 0.5f;
  float yf = (p.y + 1.0f) * scale - 0.5f;
  float zf = (p.z + 1.0f) * scale - 0.5f;
  float xi = floorf(xf), yi = floorf(yf), zi = floorf(zf);
  float fx = xf - xi, fy = yf - yi, fz = zf - zi;

  // grid row order: p = (gx<<2)|(gy<<1)|gz
  int gx = (l >> 2) & 1, gy = (l >> 1) & 1, gz = l & 1;
  int ix = (int)xi + gx;
  int iy = (int)yi + gy;
  int iz = (int)zi + gz;
  int b = (int)p.w;

  // Morton key, identical bit ops to the reference (arithmetic >> handles -1)
  int key = b << (3 * depth);
  #pragma unroll 8
  for (int d = 0; d < depth; ++d) {
    key |= ((ix >> d) & 1) << (3 * d + 2);
    key |= ((iy >> d) & 1) << (3 * d + 1);
    key |= ((iz >> d) & 1) << (3 * d);
  }

  // searchsorted (side=left), bucket-accelerated
  int lo = 0, hi = H;
  if (tab) {
    unsigned bkt = ((unsigned)key) >> S;   // key in [0, 2^kb) -> bkt < 2^K_BITS
    lo = tab[bkt];
    hi = tab[bkt + 1];
  }
  while (lo < hi) {
    int mid = (lo + hi) >> 1;
    if (keys[mid] < key) lo = mid + 1; else hi = mid;
  }
  int posc = min(lo, H - 1);

  // trilinear weight |((1-gx)-fx) * ((1-gy)-fy) * ((1-gz)-fz)|
  float wx = (1.0f - (float)gx) - fx;
  float wy = (1.0f - (float)gy) - fy;
  float wz = (1.0f - (float)gz) - fz;
  float w = fabsf((wx * wy) * wz);
  if (keys[posc] != key) w = 0.0f;  // not found -> zero weight

  // exchange (w, pos) across the aligned 8-lane group; accumulate float4
  int lane = threadIdx.x & 63;
  int base = lane & 56;
  float4 acc = make_float4(0.f, 0.f, 0.f, 0.f);
  float norm = 0.0f;
  #pragma unroll
  for (int q = 0; q < 8; ++q) {
    float wq = __shfl(w, base + q, 64);
    int   pq = __shfl(posc, base + q, 64);
    norm += wq;
    if (wq != 0.0f) {  // skip gather when weight is exactly 0 (identical math)
      float4 f = reinterpret_cast<const float4*>(data)[pq * 8 + l];
      acc.x += wq * f.x;
      acc.y += wq * f.y;
      acc.z += wq * f.z;
      acc.w += wq * f.w;
    }
  }
  float dnm = norm + 1e-12f;
  float4 o = make_float4(acc.x / dnm, acc.y / dnm, acc.z / dnm, acc.w / dnm);
  reinterpret_cast<float4*>(out)[i * 8 + l] = o;
}

// ---------------------------------------------------------------------------
// Generic-C fallback (defensive; reference uses C=32 so this should not run)
// ---------------------------------------------------------------------------
__global__ __launch_bounds__(256) void octi_interp_gen(
    const float* __restrict__ data, const float* __restrict__ pts,
    const int* __restrict__ keys, const int* __restrict__ depth_ptr,
    const int* __restrict__ tab, float* __restrict__ out,
    int N, int H, int C) {
  int i = blockIdx.x * 256 + threadIdx.x;
  if (i >= N) return;
  int depth = *depth_ptr;
  int kb = 3 * depth + 2;
  int S = kb > K_BITS ? kb - K_BITS : 0;
  float scale = (float)(1 << (depth - 1));
  float4 p = reinterpret_cast<const float4*>(pts)[i];
  float xf = (p.x + 1.0f) * scale - 0.5f;
  float yf = (p.y + 1.0f) * scale - 0.5f;
  float zf = (p.z + 1.0f) * scale - 0.5f;
  float xi = floorf(xf), yi = floorf(yf), zi = floorf(zf);
  float fx = xf - xi, fy = yf - yi, fz = zf - zi;
  int b = (int)p.w;
  float wv[8]; int pv[8];
  float norm = 0.0f;
  for (int l = 0; l < 8; ++l) {
    int gx = (l >> 2) & 1, gy = (l >> 1) & 1, gz = l & 1;
    int ix = (int)xi + gx, iy = (int)yi + gy, iz = (int)zi + gz;
    int key = b << (3 * depth);
    for (int d = 0; d < depth; ++d) {
      key |= ((ix >> d) & 1) << (3 * d + 2);
      key |= ((iy >> d) & 1) << (3 * d + 1);
      key |= ((iz >> d) & 1) << (3 * d);
    }
    int lo = 0, hi = H;
    if (tab) { unsigned bkt = ((unsigned)key) >> S; lo = tab[bkt]; hi = tab[bkt + 1]; }
    while (lo < hi) { int mid = (lo + hi) >> 1; if (keys[mid] < key) lo = mid + 1; else hi = mid; }
    int posc = min(lo, H - 1);
    float wx = (1.0f - (float)gx) - fx;
    float wy = (1.0f - (float)gy) - fy;
    float wz = (1.0f - (float)gz) - fz;
    float w = fabsf((wx * wy) * wz);
    if (keys[posc] != key) w = 0.0f;
    wv[l] = w; pv[l] = posc; norm += w;
  }
  float dnm = norm + 1e-12f;
  for (int c = 0; c < C; ++c) {
    float acc = 0.0f;
    for (int q = 0; q < 8; ++q)
      if (wv[q] != 0.0f) acc += wv[q] * data[(long long)pv[q] * C + c];
    out[(long long)i * C + c] = acc / dnm;
  }
}

extern "C" void kernel_launch(void* const* d_in, const int* in_sizes, int n_in,
                              void* d_out, int out_size, void* d_ws, size_t ws_size,
                              hipStream_t stream) {
  const float* data = (const float*)d_in[0];
  const float* pts  = (const float*)d_in[1];
  const int*   keys = (const int*)d_in[2];
  const int*   dep  = (const int*)d_in[3];
  float* out = (float*)d_out;

  int H = in_sizes[2];
  int N = in_sizes[1] / 4;
  int C = (H > 0) ? in_sizes[0] / H : 0;

  const int NB = 1 << K_BITS;
  int* tab = (int*)d_ws;
  bool useTab = ws_size >= (size_t)(NB + 1) * sizeof(int);

  if (useTab) {
    int threads = NB + 1;
    octi_build_tab<<<(threads + 255) / 256, 256, 0, stream>>>(keys, H, dep, tab);
  }

  if (C == 32) {
    long long tt = (long long)N * 8;
    int blocks = (int)((tt + 255) / 256);
    octi_interp32<<<blocks, 256, 0, stream>>>(
        data, pts, keys, dep, useTab ? tab : nullptr, out, N, H);
  } else {
    int blocks = (N + 255) / 256;
    octi_interp_gen<<<blocks, 256, 0, stream>>>(
        data, pts, keys, dep, useTab ? tab : nullptr, out, N, H, C);
  }
}